// Round 12
// baseline (469.579 us; speedup 1.0000x reference)
//
#include <hip/hip_runtime.h>
#include <math.h>

typedef _Float16 f16;
typedef _Float16 f16x4 __attribute__((ext_vector_type(4)));
typedef _Float16 f16x8 __attribute__((ext_vector_type(8)));
typedef float f32x4 __attribute__((ext_vector_type(4)));

#define SEQ   2048
#define DIM   1024
#define NH    16
#define DH    64
#define NCOLS 6144
#define NHSD  (NH*SEQ*DH)   /* 2,097,152 elements per qkv sub-tensor */
#define NTILE 136           /* tiles per head per tensor (triangular) */
#define MAXS  9
#define SLOTS_PER_HEAD 64   /* sum over I of NS2[I>>1] */

// R12 pair-splits: pair a = (I0=2a, I1=2a+1), cost T(2a+2) steps; NS2 K-splits per pair.
__device__ __forceinline__ int ns2(int a) {
  const int NS2[8] = {1,1,2,3,4,5,7,9};
  return NS2[a];
}
__device__ __forceinline__ int slot_base(int I) {  // prefix of NS2[I'>>1] over I' < I
  const int PF[16] = {0,1,2,3,4,6,8,11,14,18,22,27,32,39,46,55};
  return PF[I];
}

// ------------- transpose + cast: out[c][r] = (f16) in[r][c], in is R x C -------------
__global__ __launch_bounds__(256) void k_tcast(const float* __restrict__ in, f16* __restrict__ out,
                                               int R, int C) {
  __shared__ f16 t[64 * 66];
  int bc = blockIdx.x, br = blockIdx.y;
  for (int it = 0; it < 16; ++it) {
    int idx = it * 256 + threadIdx.x;
    int r = idx >> 6, c = idx & 63;
    t[r * 66 + c] = (f16)in[(size_t)(br * 64 + r) * C + bc * 64 + c];
  }
  __syncthreads();
  for (int it = 0; it < 16; ++it) {
    int idx = it * 256 + threadIdx.x;
    int oc = idx >> 6, orr = idx & 63;
    out[(size_t)(bc * 64 + oc) * R + br * 64 + orr] = t[orr * 66 + oc];
  }
}

// ---------------- qkv GEMM: x[2048,1024](f32, cast in staging) @ WqT[6144,1024]^T ----------------
__global__ __launch_bounds__(256) void k_gemm_qkv(const float* __restrict__ x, const f16* __restrict__ B,
                                                  f16* __restrict__ q6) {
  __shared__ f16 sa[128 * 72];
  __shared__ f16 sb[128 * 72];
  int bx = blockIdx.x, by = blockIdx.y;
  int tid = threadIdx.x, w = tid >> 6, l = tid & 63, q = l >> 4, c = l & 15;
  f32x4 acc[2][8];
  const f32x4 zf = {0.f, 0.f, 0.f, 0.f};
  for (int i = 0; i < 2; ++i) for (int j = 0; j < 8; ++j) acc[i][j] = zf;

  for (int kt = 0; kt < DIM / 64; ++kt) {
    __syncthreads();
#pragma unroll
    for (int it = 0; it < 4; ++it) {
      int idx = it * 256 + tid; int r = idx >> 3, ch = idx & 7;
      const float* ap = x + (size_t)(by * 128 + r) * DIM + kt * 64 + ch * 8;
      float4 lo = *(const float4*)(ap);
      float4 hi = *(const float4*)(ap + 4);
      f16x8 h;
      h[0] = (f16)lo.x; h[1] = (f16)lo.y; h[2] = (f16)lo.z; h[3] = (f16)lo.w;
      h[4] = (f16)hi.x; h[5] = (f16)hi.y; h[6] = (f16)hi.z; h[7] = (f16)hi.w;
      *(f16x8*)(sa + r * 72 + ch * 8) = h;
      *(float4*)(sb + r * 72 + ch * 8) = *(const float4*)(B + (size_t)(bx * 128 + r) * DIM + kt * 64 + ch * 8);
    }
    __syncthreads();
#pragma unroll
    for (int ks = 0; ks < 2; ++ks) {
      f16x8 af[2], bf[8];
#pragma unroll
      for (int tr = 0; tr < 2; ++tr) af[tr] = *(const f16x8*)(sa + (w * 32 + tr * 16 + c) * 72 + ks * 32 + q * 8);
#pragma unroll
      for (int tc = 0; tc < 8; ++tc) bf[tc] = *(const f16x8*)(sb + (tc * 16 + c) * 72 + ks * 32 + q * 8);
#pragma unroll
      for (int tr = 0; tr < 2; ++tr)
#pragma unroll
        for (int tc = 0; tc < 8; ++tc)
          acc[tr][tc] = __builtin_amdgcn_mfma_f32_16x16x32_f16(af[tr], bf[tc], acc[tr][tc], 0, 0, 0);
    }
  }
  // epilogue: scatter into qu(0) ku(1) vu(2) qc(3) kc(4) vcT(5); scale qu,qc by dh^-0.5
#pragma unroll
  for (int tr = 0; tr < 2; ++tr)
#pragma unroll
    for (int tc = 0; tc < 8; ++tc)
#pragma unroll
      for (int r = 0; r < 4; ++r) {
        int row = by * 128 + w * 32 + tr * 16 + q * 4 + r;
        int col = bx * 128 + tc * 16 + c;
        float v = acc[tr][tc][r];
        int t = col >> 10, head = (col >> 6) & 15, dh = col & 63;
        if (t == 0 || t == 3) v *= 0.125f;
        if (t == 5) q6[(size_t)5 * NHSD + (size_t)(head * DH + dh) * SEQ + row] = (f16)v;
        else        q6[(size_t)t * NHSD + (size_t)(head * SEQ + row) * DH + dh] = (f16)v;
      }
}

// ---------------- t1 + lk tile producer (each distinct tile computed ONCE, stored frag-ordered) ----------------
__global__ __launch_bounds__(256) void k_t1lk(const f16* __restrict__ q6, f16* __restrict__ t1T,
                                              f16* __restrict__ lkT) {
  __shared__ f16 st[128 * 128];
  int head = blockIdx.x / 272;
  int p = blockIdx.x % 272;
  bool is_lk = (p >= 136);
  int RB, CB;        // row-block (i or k), col-block (j)
  f16* dst;
  if (is_lk) {
    int p2 = p - 136;
    int K = 0, off = 0;
    while (off + (16 - K) <= p2) { off += 16 - K; ++K; }
    RB = K; CB = K + (p2 - off);
    dst = lkT + ((size_t)(head * NTILE + p2) << 14);
  } else {
    int I = 0;
    while ((I + 1) * (I + 2) / 2 <= p) ++I;
    RB = I; CB = p - I * (I + 1) / 2;
    dst = t1T + ((size_t)(head * NTILE + p) << 14);
  }
  const f16* Ah = q6 + (size_t)(is_lk ? 0 : 3) * NHSD + (size_t)head * SEQ * DH;  // qu_s / qc_s
  const f16* Bh = q6 + (size_t)(is_lk ? 1 : 2) * NHSD + (size_t)head * SEQ * DH;  // ku / vu
  int tid = threadIdx.x, w = tid >> 6, l = tid & 63, q = l >> 4, c = l & 15;
  const f32x4 zf = {0.f, 0.f, 0.f, 0.f};
  f32x4 tacc[2][8];
  for (int tr = 0; tr < 2; ++tr) for (int tc = 0; tc < 8; ++tc) tacc[tr][tc] = zf;
#pragma unroll
  for (int ks = 0; ks < 2; ++ks) {
    f16x8 aq[2], bf[8];
#pragma unroll
    for (int tr = 0; tr < 2; ++tr)
      aq[tr] = *(const f16x8*)(Ah + (size_t)(RB * 128 + w * 32 + tr * 16 + c) * DH + ks * 32 + q * 8);
#pragma unroll
    for (int tc = 0; tc < 8; ++tc)
      bf[tc] = *(const f16x8*)(Bh + (size_t)(CB * 128 + tc * 16 + c) * DH + ks * 32 + q * 8);
#pragma unroll
    for (int tr = 0; tr < 2; ++tr)
#pragma unroll
      for (int tc = 0; tc < 8; ++tc)
        tacc[tr][tc] = __builtin_amdgcn_mfma_f32_16x16x32_f16(aq[tr], bf[tc], tacc[tr][tc], 0, 0, 0);
  }
  // epilogue: mask (+sigmoid for lk) -> LDS row-major swizzled, own rows
#pragma unroll
  for (int tr = 0; tr < 2; ++tr)
#pragma unroll
    for (int tc = 0; tc < 8; ++tc)
#pragma unroll
      for (int r = 0; r < 4; ++r) {
        int row = w * 32 + tr * 16 + q * 4 + r;
        int col = tc * 16 + c;
        int rg = RB * 128 + row, cg = CB * 128 + col;
        float v = tacc[tr][tc][r];
        f16 ov;
        if (is_lk) ov = (cg > rg) ? (f16)__builtin_amdgcn_rcpf(1.f + __expf(-v)) : (f16)(0.f);
        else       ov = (cg <= rg) ? (f16)v : (f16)(0.f);
        st[(row << 7) + (((col >> 3) ^ (row & 15)) << 3) + (col & 7)] = ov;
      }
  __syncthreads();
  // re-read in frag order, write 16B-coalesced
#pragma unroll
  for (int i = 0; i < 8; ++i) {
    int ch = i * 256 + tid;
    int ks = ch >> 9, rb = (ch >> 6) & 7, ln = ch & 63;
    int qq = ln >> 4, cc = ln & 15;
    int row = rb * 16 + cc, cchunk = ks * 4 + qq;
    f16x8 v = *(const f16x8*)(st + (row << 7) + ((cchunk ^ (row & 15)) << 3));
    *(f16x8*)(dst + (size_t)ch * 8) = v;
  }
}

// ---------------- I-pair split-K flash (R12: 512 thr, 8 waves; one staged lk serves 2 I-tiles) ----------------
// R11's step staged 64KB for 256 block-MFMAs and the barrier's vmcnt(0) drain exposed it serially.
// R12: block = I-pair (256 rows): waves 0-3 own I0=2a, waves 4-7 own I1=2a+1. Per step: stage ONLY
// lk(K,J) (32KB) -> 512 block-MFMAs (64 B/MFMA staged, 4x better); t1 A-frags come straight from
// global (8x16B coalesced, L2-resident). Staged step count also drops 816->444/head (shared J
// stream). LDS = lkb 32K + Pb 64K (256-row P, own-wave rows) = 96K -> 1 block/CU, 2 waves/SIMD.
// Grid 512 = 16 heads x 32 pair-splits (NS2), expensive pairs dispatched first.
__global__ __launch_bounds__(512, 1) void k_flash(const f16* __restrict__ q6, const f16* __restrict__ t1T,
                                                  const f16* __restrict__ lkT,
                                                  f16* __restrict__ pO, float* __restrict__ pML) {
  __shared__ f16 lkb[128 * 128];   // staged lk tile (B-frag chunk order)
  __shared__ f16 Pb[256 * 128];    // P for both I-tiles (row-swizzled); own-wave rows only
  int bid = blockIdx.x;
  int head = ((bid & 7) << 1) | ((bid >> 3) & 1);
  int r2 = 31 - (bid >> 4);        // reversed: big pairs (a=7) dispatch first
  int a = 0, s = 0;
  {
    int acc = 0;
    for (int aa = 0; aa < 8; ++aa) {
      int si = ns2(aa);
      if (r2 >= acc && r2 < acc + si) { a = aa; s = r2 - acc; }
      acc += si;
    }
  }
  int I1 = 2 * a + 1;
  int S_ = ns2(a);
  int C = (I1 + 1) * (I1 + 2) / 2;
  int K0 = 16, K1 = 0;             // midpoint equal-cost partition of K in [0, I1]
  {
    int p = 0;
    for (int K = 0; K <= I1; ++K) {
      int cost = I1 - K + 1;
      int seg = ((2 * p + cost) * S_) / (2 * C);
      if (seg == s) { if (K < K0) K0 = K; K1 = K + 1; }
      p += cost;
    }
  }

  const f16* qc = q6 + (size_t)3 * NHSD + (size_t)head * SEQ * DH;   // pre-scaled by dh^-0.5
  const f16* kc = q6 + (size_t)4 * NHSD + (size_t)head * SEQ * DH;
  const f16* vt = q6 + (size_t)5 * NHSD + (size_t)head * DH * SEQ;   // vc transposed [64][2048]
  int tid = threadIdx.x, w = tid >> 6, l = tid & 63, q = l >> 4, c = l & 15;
  int wi = w & 3, big = w >> 2;
  int IB = 2 * a + big;            // this wave's I-tile
  const f16* t1h = t1T + ((size_t)(head * NTILE + IB * (IB + 1) / 2) << 14);

  // qc_s(IB) A-frags for the Sc MFMA (this wave's 32 rows)
  f16x8 a_qc[2][2];
#pragma unroll
  for (int tr = 0; tr < 2; ++tr)
#pragma unroll
    for (int ks = 0; ks < 2; ++ks)
      a_qc[tr][ks] = *(const f16x8*)(qc + (size_t)(IB * 128 + wi * 32 + tr * 16 + c) * DH + ks * 32 + q * 8);

  f32x4 su[2][8], oacc[2][4];
  float m_i[2][4], l_i[2][4];
  const f32x4 zf = {0.f, 0.f, 0.f, 0.f};
  for (int tr = 0; tr < 2; ++tr) for (int tv = 0; tv < 4; ++tv) oacc[tr][tv] = zf;
  for (int tr = 0; tr < 2; ++tr) for (int r = 0; r < 4; ++r) { m_i[tr][r] = -INFINITY; l_i[tr][r] = 0.f; }

  for (int K = K0; K < K1; ++K) {
    int offK = 16 * K - (K * (K - 1)) / 2;
#pragma unroll
    for (int tr = 0; tr < 2; ++tr) for (int tc = 0; tc < 8; ++tc) su[tr][tc] = zf;

    for (int J = K; J <= I1; ++J) {
      const f16* lt = lkT + ((size_t)(head * NTILE + offK + (J - K)) << 14);
      __syncthreads();   // WAR: prior Su ds_reads of lkb complete
#pragma unroll
      for (int i = 0; i < 4; ++i) {   // 512 thr x 4 x 16B = 32KB
        int e = (i * 512 + tid) * 8;
        __builtin_amdgcn_global_load_lds((const __attribute__((address_space(1))) void*)(lt + e),
                                         (__attribute__((address_space(3))) void*)(lkb + e), 16, 0, 0);
      }
      __syncthreads();   // RAW: staged tile visible (drains vmcnt)

      if (J <= IB) {     // wave-uniform: I0 waves skip J = I1
        const f16* tt = t1h + ((size_t)J << 14);
#pragma unroll
        for (int ks = 0; ks < 4; ++ks) {
          f16x8 af[2], bf[8];
#pragma unroll
          for (int tr = 0; tr < 2; ++tr)
            af[tr] = *(const f16x8*)(tt + (size_t)((ks * 8 + wi * 2 + tr) * 64 + l) * 8);
#pragma unroll
          for (int tc = 0; tc < 8; ++tc)
            bf[tc] = *(const f16x8*)(lkb + ((ks * 8 + tc) * 64 + l) * 8);
#pragma unroll
          for (int tr = 0; tr < 2; ++tr)
#pragma unroll
            for (int tc = 0; tc < 8; ++tc)
              su[tr][tc] = __builtin_amdgcn_mfma_f32_16x16x32_f16(af[tr], bf[tc], su[tr][tc], 0, 0, 0);
        }
      }
    }

    if (K <= IB) {       // wave-uniform epilogue; K=I1 contributes nothing to I0 waves
      // scores = Sc - silu(Su)
#pragma unroll
      for (int tr = 0; tr < 2; ++tr)
#pragma unroll
        for (int tc = 0; tc < 8; ++tc)
#pragma unroll
          for (int r = 0; r < 4; ++r) {
            float v = su[tr][tc][r];
            su[tr][tc][r] = -v * __builtin_amdgcn_rcpf(1.f + __expf(-v));
          }
#pragma unroll
      for (int ks = 0; ks < 2; ++ks) {
        f16x8 bk[8];
#pragma unroll
        for (int tc = 0; tc < 8; ++tc)
          bk[tc] = *(const f16x8*)(kc + (size_t)(K * 128 + tc * 16 + c) * DH + ks * 32 + q * 8);
#pragma unroll
        for (int tr = 0; tr < 2; ++tr)
#pragma unroll
          for (int tc = 0; tc < 8; ++tc)
            su[tr][tc] = __builtin_amdgcn_mfma_f32_16x16x32_f16(a_qc[tr][ks], bk[tc], su[tr][tc], 0, 0, 0);
      }
      if (K == IB) {     // strict causal mask inside the diagonal block
#pragma unroll
        for (int tr = 0; tr < 2; ++tr)
#pragma unroll
          for (int tc = 0; tc < 8; ++tc)
#pragma unroll
            for (int r = 0; r < 4; ++r) {
              int rg = wi * 32 + tr * 16 + q * 4 + r;
              int cg = tc * 16 + c;
              if (cg > rg) su[tr][tc][r] = -INFINITY;
            }
      }
      // online softmax (per-row, shuffle across low-4 lane bits)
#pragma unroll
      for (int tr = 0; tr < 2; ++tr)
#pragma unroll
        for (int r = 0; r < 4; ++r) {
          float mx = su[tr][0][r];
#pragma unroll
          for (int tc = 1; tc < 8; ++tc) mx = fmaxf(mx, su[tr][tc][r]);
          mx = fmaxf(mx, __shfl_xor(mx, 1)); mx = fmaxf(mx, __shfl_xor(mx, 2));
          mx = fmaxf(mx, __shfl_xor(mx, 4)); mx = fmaxf(mx, __shfl_xor(mx, 8));
          float mnew  = fmaxf(m_i[tr][r], mx);
          float alpha = __expf(m_i[tr][r] - mnew);
          float ssum = 0.f;
#pragma unroll
          for (int tc = 0; tc < 8; ++tc) {
            float pp = __expf(su[tr][tc][r] - mnew);
            su[tr][tc][r] = pp;
            ssum += pp;
          }
          ssum += __shfl_xor(ssum, 1); ssum += __shfl_xor(ssum, 2);
          ssum += __shfl_xor(ssum, 4); ssum += __shfl_xor(ssum, 8);
          l_i[tr][r] = l_i[tr][r] * alpha + ssum;
          m_i[tr][r] = mnew;
#pragma unroll
          for (int tv = 0; tv < 4; ++tv) oacc[tr][tv][r] *= alpha;
        }
      // P -> Pb (own 32-row region of the 256-row buffer; no barrier)
#pragma unroll
      for (int tr = 0; tr < 2; ++tr)
#pragma unroll
        for (int tc = 0; tc < 8; ++tc)
#pragma unroll
          for (int r = 0; r < 4; ++r) {
            int row = w * 32 + tr * 16 + q * 4 + r;    // 0..255
            int col = tc * 16 + c;
            Pb[(row << 7) + (((col >> 3) ^ (row & 15)) << 3) + (col & 7)] = (f16)su[tr][tc][r];
          }
      // PV: A = P (own Pb rows), B = vcT from global
#pragma unroll
      for (int ks = 0; ks < 4; ++ks) {
        int ck = ks * 4 + q;
        f16x8 af[2], bv[4];
#pragma unroll
        for (int tr = 0; tr < 2; ++tr)
          af[tr] = *(const f16x8*)(Pb + ((w * 32 + tr * 16 + c) << 7) + ((ck ^ c) << 3));
#pragma unroll
        for (int tv = 0; tv < 4; ++tv)
          bv[tv] = *(const f16x8*)(vt + (size_t)(tv * 16 + c) * SEQ + K * 128 + ks * 32 + q * 8);
#pragma unroll
        for (int tr = 0; tr < 2; ++tr)
#pragma unroll
          for (int tv = 0; tv < 4; ++tv)
            oacc[tr][tv] = __builtin_amdgcn_mfma_f32_16x16x32_f16(af[tr], bv[tv], oacc[tr][tv], 0, 0, 0);
      }
    }
  }

  // ---- unnormalized partial: slot = head*64 + prefix(IB) + s ----
  int slot = head * SLOTS_PER_HEAD + slot_base(IB) + s;
  f16* po = pO + (size_t)slot * (128 * 64);
  float* pml = pML + (size_t)slot * 256;
  if (c == 0) {
#pragma unroll
    for (int tr = 0; tr < 2; ++tr)
#pragma unroll
      for (int r = 0; r < 4; ++r) {
        int row = wi * 32 + tr * 16 + q * 4 + r;
        pml[row] = m_i[tr][r];
        pml[128 + row] = l_i[tr][r];
      }
  }
#pragma unroll
  for (int tr = 0; tr < 2; ++tr)
#pragma unroll
    for (int tv = 0; tv < 4; ++tv)
#pragma unroll
      for (int r = 0; r < 4; ++r) {
        int row = wi * 32 + tr * 16 + q * 4 + r;
        int col = tv * 16 + c;
        po[row * 64 + col] = (f16)oacc[tr][tv][r];
      }
}

// ---------------- merge partials -> oh [2048][1024] f16 ----------------
__global__ __launch_bounds__(256) void k_merge(const f16* __restrict__ pO, const float* __restrict__ pML,
                                               f16* __restrict__ oh) {
  int head = blockIdx.x >> 4, I = blockIdx.x & 15;
  int S_ = ns2(I >> 1);
  int tid = threadIdx.x;
  int row = tid >> 1, half = tid & 1;
  int base = head * SLOTS_PER_HEAD + slot_base(I);
  float m[MAXS], lv[MAXS];
  float mstar = -INFINITY;
#pragma unroll
  for (int s = 0; s < MAXS; ++s)
    if (s < S_) {
      m[s] = pML[(size_t)(base + s) * 256 + row];
      lv[s] = pML[(size_t)(base + s) * 256 + 128 + row];
      mstar = fmaxf(mstar, m[s]);
    }
  float wt[MAXS];
  float lsum = 0.f;
#pragma unroll
  for (int s = 0; s < MAXS; ++s)
    if (s < S_) {
      wt[s] = __expf(m[s] - mstar);   // empty partials (m=-inf) get weight 0
      lsum += lv[s] * wt[s];
    }
  float rinv = __builtin_amdgcn_rcpf(lsum);
#pragma unroll
  for (int cc = 0; cc < 32; cc += 8) {
    float acc[8] = {0.f, 0.f, 0.f, 0.f, 0.f, 0.f, 0.f, 0.f};
#pragma unroll
    for (int s = 0; s < MAXS; ++s)
      if (s < S_) {
        f16x8 v = *(const f16x8*)(pO + (size_t)(base + s) * 8192 + row * 64 + half * 32 + cc);
#pragma unroll
        for (int e = 0; e < 8; ++e) acc[e] += wt[s] * (float)v[e];
      }
    f16x8 o;
#pragma unroll
    for (int e = 0; e < 8; ++e) o[e] = (f16)(acc[e] * rinv);
    *(f16x8*)(oh + (size_t)(I * 128 + row) * DIM + head * 64 + half * 32 + cc) = o;
  }
}

// ---------------- final GEMM: oh[2048,1024] @ WoT[1024,1024]^T -> fp32 out ----------------
__global__ __launch_bounds__(256) void k_gemm_out(const f16* __restrict__ A, const f16* __restrict__ B,
                                                  float* __restrict__ out) {
  __shared__ f16 sa[128 * 72];
  __shared__ f16 sb[128 * 72];
  int bx = blockIdx.x, by = blockIdx.y;
  int tid = threadIdx.x, w = tid >> 6, l = tid & 63, q = l >> 4, c = l & 15;
  f32x4 acc[2][8];
  const f32x4 zf = {0.f, 0.f, 0.f, 0.f};
  for (int i = 0; i < 2; ++i) for (int j = 0; j < 8; ++j) acc[i][j] = zf;
  for (int kt = 0; kt < DIM / 64; ++kt) {
    __syncthreads();
#pragma unroll
    for (int it = 0; it < 4; ++it) {
      int idx = it * 256 + tid; int r = idx >> 3, ch = idx & 7;
      *(float4*)(sa + r * 72 + ch * 8) = *(const float4*)(A + (size_t)(by * 128 + r) * DIM + kt * 64 + ch * 8);
      *(float4*)(sb + r * 72 + ch * 8) = *(const float4*)(B + (size_t)(bx * 128 + r) * DIM + kt * 64 + ch * 8);
    }
    __syncthreads();
#pragma unroll
    for (int ks = 0; ks < 2; ++ks) {
      f16x8 af[2], bf[8];
#pragma unroll
      for (int tr = 0; tr < 2; ++tr) af[tr] = *(const f16x8*)(sa + (w * 32 + tr * 16 + c) * 72 + ks * 32 + q * 8);
#pragma unroll
      for (int tc = 0; tc < 8; ++tc) bf[tc] = *(const f16x8*)(sb + (tc * 16 + c) * 72 + ks * 32 + q * 8);
#pragma unroll
      for (int tr = 0; tr < 2; ++tr)
#pragma unroll
        for (int tc = 0; tc < 8; ++tc)
          acc[tr][tc] = __builtin_amdgcn_mfma_f32_16x16x32_f16(af[tr], bf[tc], acc[tr][tc], 0, 0, 0);
    }
  }
#pragma unroll
  for (int tr = 0; tr < 2; ++tr)
#pragma unroll
    for (int tc = 0; tc < 8; ++tc)
#pragma unroll
      for (int r = 0; r < 4; ++r) {
        int row = by * 128 + w * 32 + tr * 16 + q * 4 + r;
        int col = bx * 128 + tc * 16 + c;
        out[(size_t)row * DIM + col] = acc[tr][tc][r];
      }
}

extern "C" void kernel_launch(void* const* d_in, const int* in_sizes, int n_in,
                              void* d_out, int out_size, void* d_ws, size_t ws_size,
                              hipStream_t stream) {
  const float* x  = (const float*)d_in[0];
  const float* Wq = (const float*)d_in[1];
  const float* Wo = (const float*)d_in[2];
  float* out = (float*)d_out;

  f16* ws = (f16*)d_ws;
  size_t off = 0;
  f16* q6  = ws + off; off += (size_t)6 * NHSD;                        // 25.2 MB
  f16* WqT = ws + off; off += (size_t)NCOLS * DIM;                     // 12.6 MB
  f16* WoT = ws + off; off += (size_t)DIM * DIM;                       // 2.1 MB
  f16* oh  = ws + off; off += (size_t)SEQ * DIM;                       // 4.2 MB
  f16* pO  = ws + off; off += (size_t)NH * SLOTS_PER_HEAD * 128 * 64;  // 16.8 MB
  f16* lkT = ws + off; off += (size_t)NH * NTILE * 128 * 128;          // 71.3 MB
  f16* t1T = ws + off; off += (size_t)NH * NTILE * 128 * 128;          // 71.3 MB
  float* pML = (float*)(ws + off); off += (size_t)NH * SLOTS_PER_HEAD * 256 * 2; // 1.05 MB
  // total ~205 MB of workspace

  k_tcast<<<dim3(NCOLS / 64, DIM / 64), 256, 0, stream>>>(Wq, WqT, DIM, NCOLS);
  k_tcast<<<dim3(DIM / 64, DIM / 64), 256, 0, stream>>>(Wo, WoT, DIM, DIM);
  k_gemm_qkv<<<dim3(NCOLS / 128, SEQ / 128), 256, 0, stream>>>(x, WqT, q6);
  k_t1lk<<<NH * 272, 256, 0, stream>>>(q6, t1T, lkT);
  k_flash<<<NH * 32, 512, 0, stream>>>(q6, t1T, lkT, pO, pML);
  k_merge<<<NH * 16, 256, 0, stream>>>(pO, pML, oh);
  k_gemm_out<<<dim3(DIM / 128, SEQ / 128), 256, 0, stream>>>(oh, WoT, out);
}

// Round 13
// 469.080 us; speedup vs baseline: 1.0011x; 1.0011x over previous
//
#include <hip/hip_runtime.h>
#include <math.h>

typedef _Float16 f16;
typedef _Float16 f16x4 __attribute__((ext_vector_type(4)));
typedef _Float16 f16x8 __attribute__((ext_vector_type(8)));
typedef float f32x4 __attribute__((ext_vector_type(4)));

#define SEQ   2048
#define DIM   1024
#define NH    16
#define DH    64
#define NCOLS 6144
#define NHSD  (NH*SEQ*DH)   /* 2,097,152 elements per qkv sub-tensor */
#define NTILE 136           /* tiles per head per tensor (triangular) */
#define MAXS  9
#define SLOTS_PER_HEAD 64   /* sum over I of NS2[I>>1] */

// pair-splits: pair a = (I0=2a, I1=2a+1), cost T(2a+2) steps; NS2 K-splits per pair.
__device__ __forceinline__ int ns2(int a) {
  const int NS2[8] = {1,1,2,3,4,5,7,9};
  return NS2[a];
}
__device__ __forceinline__ int slot_base(int I) {  // prefix of NS2[I'>>1] over I' < I
  const int PF[16] = {0,1,2,3,4,6,8,11,14,18,22,27,32,39,46,55};
  return PF[I];
}

// ------------- transpose + cast: out[c][r] = (f16) in[r][c], in is R x C -------------
__global__ __launch_bounds__(256) void k_tcast(const float* __restrict__ in, f16* __restrict__ out,
                                               int R, int C) {
  __shared__ f16 t[64 * 66];
  int bc = blockIdx.x, br = blockIdx.y;
  for (int it = 0; it < 16; ++it) {
    int idx = it * 256 + threadIdx.x;
    int r = idx >> 6, c = idx & 63;
    t[r * 66 + c] = (f16)in[(size_t)(br * 64 + r) * C + bc * 64 + c];
  }
  __syncthreads();
  for (int it = 0; it < 16; ++it) {
    int idx = it * 256 + threadIdx.x;
    int oc = idx >> 6, orr = idx & 63;
    out[(size_t)(bc * 64 + oc) * R + br * 64 + orr] = t[orr * 66 + oc];
  }
}

// ---------------- qkv GEMM: x[2048,1024](f32, cast in staging) @ WqT[6144,1024]^T ----------------
__global__ __launch_bounds__(256) void k_gemm_qkv(const float* __restrict__ x, const f16* __restrict__ B,
                                                  f16* __restrict__ q6) {
  __shared__ f16 sa[128 * 72];
  __shared__ f16 sb[128 * 72];
  int bx = blockIdx.x, by = blockIdx.y;
  int tid = threadIdx.x, w = tid >> 6, l = tid & 63, q = l >> 4, c = l & 15;
  f32x4 acc[2][8];
  const f32x4 zf = {0.f, 0.f, 0.f, 0.f};
  for (int i = 0; i < 2; ++i) for (int j = 0; j < 8; ++j) acc[i][j] = zf;

  for (int kt = 0; kt < DIM / 64; ++kt) {
    __syncthreads();
#pragma unroll
    for (int it = 0; it < 4; ++it) {
      int idx = it * 256 + tid; int r = idx >> 3, ch = idx & 7;
      const float* ap = x + (size_t)(by * 128 + r) * DIM + kt * 64 + ch * 8;
      float4 lo = *(const float4*)(ap);
      float4 hi = *(const float4*)(ap + 4);
      f16x8 h;
      h[0] = (f16)lo.x; h[1] = (f16)lo.y; h[2] = (f16)lo.z; h[3] = (f16)lo.w;
      h[4] = (f16)hi.x; h[5] = (f16)hi.y; h[6] = (f16)hi.z; h[7] = (f16)hi.w;
      *(f16x8*)(sa + r * 72 + ch * 8) = h;
      *(float4*)(sb + r * 72 + ch * 8) = *(const float4*)(B + (size_t)(bx * 128 + r) * DIM + kt * 64 + ch * 8);
    }
    __syncthreads();
#pragma unroll
    for (int ks = 0; ks < 2; ++ks) {
      f16x8 af[2], bf[8];
#pragma unroll
      for (int tr = 0; tr < 2; ++tr) af[tr] = *(const f16x8*)(sa + (w * 32 + tr * 16 + c) * 72 + ks * 32 + q * 8);
#pragma unroll
      for (int tc = 0; tc < 8; ++tc) bf[tc] = *(const f16x8*)(sb + (tc * 16 + c) * 72 + ks * 32 + q * 8);
#pragma unroll
      for (int tr = 0; tr < 2; ++tr)
#pragma unroll
        for (int tc = 0; tc < 8; ++tc)
          acc[tr][tc] = __builtin_amdgcn_mfma_f32_16x16x32_f16(af[tr], bf[tc], acc[tr][tc], 0, 0, 0);
    }
  }
  // epilogue: scatter into qu(0) ku(1) vu(2) qc(3) kc(4) vcT(5); scale qu,qc by dh^-0.5
#pragma unroll
  for (int tr = 0; tr < 2; ++tr)
#pragma unroll
    for (int tc = 0; tc < 8; ++tc)
#pragma unroll
      for (int r = 0; r < 4; ++r) {
        int row = by * 128 + w * 32 + tr * 16 + q * 4 + r;
        int col = bx * 128 + tc * 16 + c;
        float v = acc[tr][tc][r];
        int t = col >> 10, head = (col >> 6) & 15, dh = col & 63;
        if (t == 0 || t == 3) v *= 0.125f;
        if (t == 5) q6[(size_t)5 * NHSD + (size_t)(head * DH + dh) * SEQ + row] = (f16)v;
        else        q6[(size_t)t * NHSD + (size_t)(head * SEQ + row) * DH + dh] = (f16)v;
      }
}

// ---------------- t1 + lk tile producer (each distinct tile computed ONCE, stored frag-ordered) ----------------
__global__ __launch_bounds__(256) void k_t1lk(const f16* __restrict__ q6, f16* __restrict__ t1T,
                                              f16* __restrict__ lkT) {
  __shared__ f16 st[128 * 128];
  int head = blockIdx.x / 272;
  int p = blockIdx.x % 272;
  bool is_lk = (p >= 136);
  int RB, CB;        // row-block (i or k), col-block (j)
  f16* dst;
  if (is_lk) {
    int p2 = p - 136;
    int K = 0, off = 0;
    while (off + (16 - K) <= p2) { off += 16 - K; ++K; }
    RB = K; CB = K + (p2 - off);
    dst = lkT + ((size_t)(head * NTILE + p2) << 14);
  } else {
    int I = 0;
    while ((I + 1) * (I + 2) / 2 <= p) ++I;
    RB = I; CB = p - I * (I + 1) / 2;
    dst = t1T + ((size_t)(head * NTILE + p) << 14);
  }
  const f16* Ah = q6 + (size_t)(is_lk ? 0 : 3) * NHSD + (size_t)head * SEQ * DH;  // qu_s / qc_s
  const f16* Bh = q6 + (size_t)(is_lk ? 1 : 2) * NHSD + (size_t)head * SEQ * DH;  // ku / vu
  int tid = threadIdx.x, w = tid >> 6, l = tid & 63, q = l >> 4, c = l & 15;
  const f32x4 zf = {0.f, 0.f, 0.f, 0.f};
  f32x4 tacc[2][8];
  for (int tr = 0; tr < 2; ++tr) for (int tc = 0; tc < 8; ++tc) tacc[tr][tc] = zf;
#pragma unroll
  for (int ks = 0; ks < 2; ++ks) {
    f16x8 aq[2], bf[8];
#pragma unroll
    for (int tr = 0; tr < 2; ++tr)
      aq[tr] = *(const f16x8*)(Ah + (size_t)(RB * 128 + w * 32 + tr * 16 + c) * DH + ks * 32 + q * 8);
#pragma unroll
    for (int tc = 0; tc < 8; ++tc)
      bf[tc] = *(const f16x8*)(Bh + (size_t)(CB * 128 + tc * 16 + c) * DH + ks * 32 + q * 8);
#pragma unroll
    for (int tr = 0; tr < 2; ++tr)
#pragma unroll
      for (int tc = 0; tc < 8; ++tc)
        tacc[tr][tc] = __builtin_amdgcn_mfma_f32_16x16x32_f16(aq[tr], bf[tc], tacc[tr][tc], 0, 0, 0);
  }
  // epilogue: mask (+sigmoid for lk) -> LDS row-major swizzled, own rows
#pragma unroll
  for (int tr = 0; tr < 2; ++tr)
#pragma unroll
    for (int tc = 0; tc < 8; ++tc)
#pragma unroll
      for (int r = 0; r < 4; ++r) {
        int row = w * 32 + tr * 16 + q * 4 + r;
        int col = tc * 16 + c;
        int rg = RB * 128 + row, cg = CB * 128 + col;
        float v = tacc[tr][tc][r];
        f16 ov;
        if (is_lk) ov = (cg > rg) ? (f16)__builtin_amdgcn_rcpf(1.f + __expf(-v)) : (f16)(0.f);
        else       ov = (cg <= rg) ? (f16)v : (f16)(0.f);
        st[(row << 7) + (((col >> 3) ^ (row & 15)) << 3) + (col & 7)] = ov;
      }
  __syncthreads();
  // re-read in frag order, write 16B-coalesced
#pragma unroll
  for (int i = 0; i < 8; ++i) {
    int ch = i * 256 + tid;
    int ks = ch >> 9, rb = (ch >> 6) & 7, ln = ch & 63;
    int qq = ln >> 4, cc = ln & 15;
    int row = rb * 16 + cc, cchunk = ks * 4 + qq;
    f16x8 v = *(const f16x8*)(st + (row << 7) + ((cchunk ^ (row & 15)) << 3));
    *(f16x8*)(dst + (size_t)ch * 8) = v;
  }
}

// ---------------- I-pair split-K flash (R13: DOUBLE-BUFFERED lk staging) ----------------
// R10/R11/R12 all converged at 217-235us / 1.2-1.4 TB/s: each step drains its 32KB stage at the
// barrier (vmcnt(0)) then computes with ZERO bytes in flight -> ~50% HBM duty cycle. R13 gives the
// staged load compute-duration to land: barrier -> issue prefetch(J+1) into idle buffer -> compute
// J from live buffer -> barrier. lkb[2] (64KB) + Pb (64KB) = 128KB LDS, 1 block/CU, 8 waves.
__global__ __launch_bounds__(512, 1) void k_flash(const f16* __restrict__ q6, const f16* __restrict__ t1T,
                                                  const f16* __restrict__ lkT,
                                                  f16* __restrict__ pO, float* __restrict__ pML) {
  __shared__ f16 lkb[2][128 * 128];  // double-buffered staged lk tile (B-frag chunk order)
  __shared__ f16 Pb[256 * 128];      // P for both I-tiles (row-swizzled); own-wave rows only
  int bid = blockIdx.x;
  int head = ((bid & 7) << 1) | ((bid >> 3) & 1);
  int r2 = 31 - (bid >> 4);          // reversed: big pairs (a=7) dispatch first
  int a = 0, s = 0;
  {
    int acc = 0;
    for (int aa = 0; aa < 8; ++aa) {
      int si = ns2(aa);
      if (r2 >= acc && r2 < acc + si) { a = aa; s = r2 - acc; }
      acc += si;
    }
  }
  int I1 = 2 * a + 1;
  int S_ = ns2(a);
  int C = (I1 + 1) * (I1 + 2) / 2;
  int K0 = 16, K1 = 0;               // midpoint equal-cost partition of K in [0, I1]
  {
    int p = 0;
    for (int K = 0; K <= I1; ++K) {
      int cost = I1 - K + 1;
      int seg = ((2 * p + cost) * S_) / (2 * C);
      if (seg == s) { if (K < K0) K0 = K; K1 = K + 1; }
      p += cost;
    }
  }

  const f16* qc = q6 + (size_t)3 * NHSD + (size_t)head * SEQ * DH;   // pre-scaled by dh^-0.5
  const f16* kc = q6 + (size_t)4 * NHSD + (size_t)head * SEQ * DH;
  const f16* vt = q6 + (size_t)5 * NHSD + (size_t)head * DH * SEQ;   // vc transposed [64][2048]
  int tid = threadIdx.x, w = tid >> 6, l = tid & 63, q = l >> 4, c = l & 15;
  int wi = w & 3, big = w >> 2;
  int IB = 2 * a + big;              // this wave's I-tile
  const f16* t1h = t1T + ((size_t)(head * NTILE + IB * (IB + 1) / 2) << 14);
  const f16* lkh = lkT + ((size_t)(head * NTILE) << 14);

  // qc_s(IB) A-frags for the Sc MFMA (this wave's 32 rows)
  f16x8 a_qc[2][2];
#pragma unroll
  for (int tr = 0; tr < 2; ++tr)
#pragma unroll
    for (int ks = 0; ks < 2; ++ks)
      a_qc[tr][ks] = *(const f16x8*)(qc + (size_t)(IB * 128 + wi * 32 + tr * 16 + c) * DH + ks * 32 + q * 8);

  f32x4 su[2][8], oacc[2][4];
  float m_i[2][4], l_i[2][4];
  const f32x4 zf = {0.f, 0.f, 0.f, 0.f};
  for (int tr = 0; tr < 2; ++tr) for (int tv = 0; tv < 4; ++tv) oacc[tr][tv] = zf;
  for (int tr = 0; tr < 2; ++tr) for (int r = 0; r < 4; ++r) { m_i[tr][r] = -INFINITY; l_i[tr][r] = 0.f; }

  for (int K = K0; K < K1; ++K) {
    int offK = 16 * K - (K * (K - 1)) / 2;
#pragma unroll
    for (int tr = 0; tr < 2; ++tr) for (int tc = 0; tc < 8; ++tc) su[tr][tc] = zf;

    // prologue: stage lk(K,K) into buf 0 (WAR vs previous reads handled by barrier)
    __syncthreads();
    {
      const f16* lt = lkh + ((size_t)offK << 14);
#pragma unroll
      for (int i = 0; i < 4; ++i) {
        int e = (i * 512 + tid) * 8;
        __builtin_amdgcn_global_load_lds((const __attribute__((address_space(1))) void*)(lt + e),
                                         (__attribute__((address_space(3))) void*)(&lkb[0][0] + e), 16, 0, 0);
      }
    }
    int pb = 0;
    for (int J = K; J <= I1; ++J) {
      __syncthreads();   // buf[pb] staged (vmcnt drain — prefetch had compute-duration to land)
      if (J < I1) {      // prefetch next tile into the idle buffer
        const f16* ln = lkh + ((size_t)(offK + (J + 1 - K)) << 14);
#pragma unroll
        for (int i = 0; i < 4; ++i) {
          int e = (i * 512 + tid) * 8;
          __builtin_amdgcn_global_load_lds((const __attribute__((address_space(1))) void*)(ln + e),
                                           (__attribute__((address_space(3))) void*)(&lkb[pb ^ 1][0] + e), 16, 0, 0);
        }
      }
      if (J <= IB) {     // wave-uniform: I0 waves skip J = I1
        const f16* tt = t1h + ((size_t)J << 14);
#pragma unroll
        for (int ks = 0; ks < 4; ++ks) {
          f16x8 af[2], bf[8];
#pragma unroll
          for (int tr = 0; tr < 2; ++tr)
            af[tr] = *(const f16x8*)(tt + (size_t)((ks * 8 + wi * 2 + tr) * 64 + l) * 8);
#pragma unroll
          for (int tc = 0; tc < 8; ++tc)
            bf[tc] = *(const f16x8*)(&lkb[pb][0] + ((ks * 8 + tc) * 64 + l) * 8);
#pragma unroll
          for (int tr = 0; tr < 2; ++tr)
#pragma unroll
            for (int tc = 0; tc < 8; ++tc)
              su[tr][tc] = __builtin_amdgcn_mfma_f32_16x16x32_f16(af[tr], bf[tc], su[tr][tc], 0, 0, 0);
        }
      }
      pb ^= 1;
    }

    if (K <= IB) {       // wave-uniform epilogue; K=I1 contributes nothing to I0 waves
      // scores = Sc - silu(Su)
#pragma unroll
      for (int tr = 0; tr < 2; ++tr)
#pragma unroll
        for (int tc = 0; tc < 8; ++tc)
#pragma unroll
          for (int r = 0; r < 4; ++r) {
            float v = su[tr][tc][r];
            su[tr][tc][r] = -v * __builtin_amdgcn_rcpf(1.f + __expf(-v));
          }
#pragma unroll
      for (int ks = 0; ks < 2; ++ks) {
        f16x8 bk[8];
#pragma unroll
        for (int tc = 0; tc < 8; ++tc)
          bk[tc] = *(const f16x8*)(kc + (size_t)(K * 128 + tc * 16 + c) * DH + ks * 32 + q * 8);
#pragma unroll
        for (int tr = 0; tr < 2; ++tr)
#pragma unroll
          for (int tc = 0; tc < 8; ++tc)
            su[tr][tc] = __builtin_amdgcn_mfma_f32_16x16x32_f16(a_qc[tr][ks], bk[tc], su[tr][tc], 0, 0, 0);
      }
      if (K == IB) {     // strict causal mask inside the diagonal block
#pragma unroll
        for (int tr = 0; tr < 2; ++tr)
#pragma unroll
          for (int tc = 0; tc < 8; ++tc)
#pragma unroll
            for (int r = 0; r < 4; ++r) {
              int rg = wi * 32 + tr * 16 + q * 4 + r;
              int cg = tc * 16 + c;
              if (cg > rg) su[tr][tc][r] = -INFINITY;
            }
      }
      // online softmax (per-row, shuffle across low-4 lane bits)
#pragma unroll
      for (int tr = 0; tr < 2; ++tr)
#pragma unroll
        for (int r = 0; r < 4; ++r) {
          float mx = su[tr][0][r];
#pragma unroll
          for (int tc = 1; tc < 8; ++tc) mx = fmaxf(mx, su[tr][tc][r]);
          mx = fmaxf(mx, __shfl_xor(mx, 1)); mx = fmaxf(mx, __shfl_xor(mx, 2));
          mx = fmaxf(mx, __shfl_xor(mx, 4)); mx = fmaxf(mx, __shfl_xor(mx, 8));
          float mnew  = fmaxf(m_i[tr][r], mx);
          float alpha = __expf(m_i[tr][r] - mnew);
          float ssum = 0.f;
#pragma unroll
          for (int tc = 0; tc < 8; ++tc) {
            float pp = __expf(su[tr][tc][r] - mnew);
            su[tr][tc][r] = pp;
            ssum += pp;
          }
          ssum += __shfl_xor(ssum, 1); ssum += __shfl_xor(ssum, 2);
          ssum += __shfl_xor(ssum, 4); ssum += __shfl_xor(ssum, 8);
          l_i[tr][r] = l_i[tr][r] * alpha + ssum;
          m_i[tr][r] = mnew;
#pragma unroll
          for (int tv = 0; tv < 4; ++tv) oacc[tr][tv][r] *= alpha;
        }
      // P -> Pb (own 32-row region of the 256-row buffer; no barrier)
#pragma unroll
      for (int tr = 0; tr < 2; ++tr)
#pragma unroll
        for (int tc = 0; tc < 8; ++tc)
#pragma unroll
          for (int r = 0; r < 4; ++r) {
            int row = w * 32 + tr * 16 + q * 4 + r;    // 0..255
            int col = tc * 16 + c;
            Pb[(row << 7) + (((col >> 3) ^ (row & 15)) << 3) + (col & 7)] = (f16)su[tr][tc][r];
          }
      // PV: A = P (own Pb rows), B = vcT from global
#pragma unroll
      for (int ks = 0; ks < 4; ++ks) {
        int ck = ks * 4 + q;
        f16x8 af[2], bv[4];
#pragma unroll
        for (int tr = 0; tr < 2; ++tr)
          af[tr] = *(const f16x8*)(Pb + ((w * 32 + tr * 16 + c) << 7) + ((ck ^ c) << 3));
#pragma unroll
        for (int tv = 0; tv < 4; ++tv)
          bv[tv] = *(const f16x8*)(vt + (size_t)(tv * 16 + c) * SEQ + K * 128 + ks * 32 + q * 8);
#pragma unroll
        for (int tr = 0; tr < 2; ++tr)
#pragma unroll
          for (int tv = 0; tv < 4; ++tv)
            oacc[tr][tv] = __builtin_amdgcn_mfma_f32_16x16x32_f16(af[tr], bv[tv], oacc[tr][tv], 0, 0, 0);
      }
    }
  }

  // ---- unnormalized partial: slot = head*64 + prefix(IB) + s ----
  int slot = head * SLOTS_PER_HEAD + slot_base(IB) + s;
  f16* po = pO + (size_t)slot * (128 * 64);
  float* pml = pML + (size_t)slot * 256;
  if (c == 0) {
#pragma unroll
    for (int tr = 0; tr < 2; ++tr)
#pragma unroll
      for (int r = 0; r < 4; ++r) {
        int row = wi * 32 + tr * 16 + q * 4 + r;
        pml[row] = m_i[tr][r];
        pml[128 + row] = l_i[tr][r];
      }
  }
#pragma unroll
  for (int tr = 0; tr < 2; ++tr)
#pragma unroll
    for (int tv = 0; tv < 4; ++tv)
#pragma unroll
      for (int r = 0; r < 4; ++r) {
        int row = wi * 32 + tr * 16 + q * 4 + r;
        int col = tv * 16 + c;
        po[row * 64 + col] = (f16)oacc[tr][tv][r];
      }
}

// ---------------- merge partials -> oh [2048][1024] f16 ----------------
__global__ __launch_bounds__(256) void k_merge(const f16* __restrict__ pO, const float* __restrict__ pML,
                                               f16* __restrict__ oh) {
  int head = blockIdx.x >> 4, I = blockIdx.x & 15;
  int S_ = ns2(I >> 1);
  int tid = threadIdx.x;
  int row = tid >> 1, half = tid & 1;
  int base = head * SLOTS_PER_HEAD + slot_base(I);
  float m[MAXS], lv[MAXS];
  float mstar = -INFINITY;
#pragma unroll
  for (int s = 0; s < MAXS; ++s)
    if (s < S_) {
      m[s] = pML[(size_t)(base + s) * 256 + row];
      lv[s] = pML[(size_t)(base + s) * 256 + 128 + row];
      mstar = fmaxf(mstar, m[s]);
    }
  float wt[MAXS];
  float lsum = 0.f;
#pragma unroll
  for (int s = 0; s < MAXS; ++s)
    if (s < S_) {
      wt[s] = __expf(m[s] - mstar);   // empty partials (m=-inf) get weight 0
      lsum += lv[s] * wt[s];
    }
  float rinv = __builtin_amdgcn_rcpf(lsum);
#pragma unroll
  for (int cc = 0; cc < 32; cc += 8) {
    float acc[8] = {0.f, 0.f, 0.f, 0.f, 0.f, 0.f, 0.f, 0.f};
#pragma unroll
    for (int s = 0; s < MAXS; ++s)
      if (s < S_) {
        f16x8 v = *(const f16x8*)(pO + (size_t)(base + s) * 8192 + row * 64 + half * 32 + cc);
#pragma unroll
        for (int e = 0; e < 8; ++e) acc[e] += wt[s] * (float)v[e];
      }
    f16x8 o;
#pragma unroll
    for (int e = 0; e < 8; ++e) o[e] = (f16)(acc[e] * rinv);
    *(f16x8*)(oh + (size_t)(I * 128 + row) * DIM + head * 64 + half * 32 + cc) = o;
  }
}

// ---------------- final GEMM: oh[2048,1024] @ WoT[1024,1024]^T -> fp32 out ----------------
__global__ __launch_bounds__(256) void k_gemm_out(const f16* __restrict__ A, const f16* __restrict__ B,
                                                  float* __restrict__ out) {
  __shared__ f16 sa[128 * 72];
  __shared__ f16 sb[128 * 72];
  int bx = blockIdx.x, by = blockIdx.y;
  int tid = threadIdx.x, w = tid >> 6, l = tid & 63, q = l >> 4, c = l & 15;
  f32x4 acc[2][8];
  const f32x4 zf = {0.f, 0.f, 0.f, 0.f};
  for (int i = 0; i < 2; ++i) for (int j = 0; j < 8; ++j) acc[i][j] = zf;
  for (int kt = 0; kt < DIM / 64; ++kt) {
    __syncthreads();
#pragma unroll
    for (int it = 0; it < 4; ++it) {
      int idx = it * 256 + tid; int r = idx >> 3, ch = idx & 7;
      *(float4*)(sa + r * 72 + ch * 8) = *(const float4*)(A + (size_t)(by * 128 + r) * DIM + kt * 64 + ch * 8);
      *(float4*)(sb + r * 72 + ch * 8) = *(const float4*)(B + (size_t)(bx * 128 + r) * DIM + kt * 64 + ch * 8);
    }
    __syncthreads();
#pragma unroll
    for (int ks = 0; ks < 2; ++ks) {
      f16x8 af[2], bf[8];
#pragma unroll
      for (int tr = 0; tr < 2; ++tr) af[tr] = *(const f16x8*)(sa + (w * 32 + tr * 16 + c) * 72 + ks * 32 + q * 8);
#pragma unroll
      for (int tc = 0; tc < 8; ++tc) bf[tc] = *(const f16x8*)(sb + (tc * 16 + c) * 72 + ks * 32 + q * 8);
#pragma unroll
      for (int tr = 0; tr < 2; ++tr)
#pragma unroll
        for (int tc = 0; tc < 8; ++tc)
          acc[tr][tc] = __builtin_amdgcn_mfma_f32_16x16x32_f16(af[tr], bf[tc], acc[tr][tc], 0, 0, 0);
    }
  }
#pragma unroll
  for (int tr = 0; tr < 2; ++tr)
#pragma unroll
    for (int tc = 0; tc < 8; ++tc)
#pragma unroll
      for (int r = 0; r < 4; ++r) {
        int row = by * 128 + w * 32 + tr * 16 + q * 4 + r;
        int col = bx * 128 + tc * 16 + c;
        out[(size_t)row * DIM + col] = acc[tr][tc][r];
      }
}

extern "C" void kernel_launch(void* const* d_in, const int* in_sizes, int n_in,
                              void* d_out, int out_size, void* d_ws, size_t ws_size,
                              hipStream_t stream) {
  const float* x  = (const float*)d_in[0];
  const float* Wq = (const float*)d_in[1];
  const float* Wo = (const float*)d_in[2];
  float* out = (float*)d_out;

  f16* ws = (f16*)d_ws;
  size_t off = 0;
  f16* q6  = ws + off; off += (size_t)6 * NHSD;                        // 25.2 MB
  f16* WqT = ws + off; off += (size_t)NCOLS * DIM;                     // 12.6 MB
  f16* WoT = ws + off; off += (size_t)DIM * DIM;                       // 2.1 MB
  f16* oh  = ws + off; off += (size_t)SEQ * DIM;                       // 4.2 MB
  f16* pO  = ws + off; off += (size_t)NH * SLOTS_PER_HEAD * 128 * 64;  // 16.8 MB
  f16* lkT = ws + off; off += (size_t)NH * NTILE * 128 * 128;          // 71.3 MB
  f16* t1T = ws + off; off += (size_t)NH * NTILE * 128 * 128;          // 71.3 MB
  float* pML = (float*)(ws + off); off += (size_t)NH * SLOTS_PER_HEAD * 256 * 2; // 1.05 MB
  // total ~205 MB of workspace

  k_tcast<<<dim3(NCOLS / 64, DIM / 64), 256, 0, stream>>>(Wq, WqT, DIM, NCOLS);
  k_tcast<<<dim3(DIM / 64, DIM / 64), 256, 0, stream>>>(Wo, WoT, DIM, DIM);
  k_gemm_qkv<<<dim3(NCOLS / 128, SEQ / 128), 256, 0, stream>>>(x, WqT, q6);
  k_t1lk<<<NH * 272, 256, 0, stream>>>(q6, t1T, lkT);
  k_flash<<<NH * 32, 512, 0, stream>>>(q6, t1T, lkT, pO, pML);
  k_merge<<<NH * 16, 256, 0, stream>>>(pO, pML, oh);
  k_gemm_out<<<dim3(DIM / 128, SEQ / 128), 256, 0, stream>>>(oh, WoT, out);
}

// Round 14
// 435.879 us; speedup vs baseline: 1.0773x; 1.0762x over previous
//
#include <hip/hip_runtime.h>
#include <math.h>

typedef _Float16 f16;
typedef _Float16 f16x4 __attribute__((ext_vector_type(4)));
typedef _Float16 f16x8 __attribute__((ext_vector_type(8)));
typedef float f32x4 __attribute__((ext_vector_type(4)));

#define SEQ   2048
#define DIM   1024
#define NH    16
#define DH    64
#define NCOLS 6144
#define NHSD  (NH*SEQ*DH)   /* 2,097,152 elements per qkv sub-tensor */
#define NTILE 136           /* tiles per head per tensor (triangular) */
#define MAXS  9
#define SLOTS_PER_HEAD 64   /* sum over I of NS2[I>>1] */

// pair-splits: pair a = (I0=2a, I1=2a+1), cost T(2a+2) steps; NS2 K-splits per pair.
__device__ __forceinline__ int ns2(int a) {
  const int NS2[8] = {1,1,2,3,4,5,7,9};
  return NS2[a];
}
__device__ __forceinline__ int slot_base(int I) {  // prefix of NS2[I'>>1] over I' < I
  const int PF[16] = {0,1,2,3,4,6,8,11,14,18,22,27,32,39,46,55};
  return PF[I];
}

// ------------- transpose + cast: out[c][r] = (f16) in[r][c], in is R x C (Wo only) -------------
__global__ __launch_bounds__(256) void k_tcast(const float* __restrict__ in, f16* __restrict__ out,
                                               int R, int C) {
  __shared__ f16 t[64 * 66];
  int bc = blockIdx.x, br = blockIdx.y;
  for (int it = 0; it < 16; ++it) {
    int idx = it * 256 + threadIdx.x;
    int r = idx >> 6, c = idx & 63;
    t[r * 66 + c] = (f16)in[(size_t)(br * 64 + r) * C + bc * 64 + c];
  }
  __syncthreads();
  for (int it = 0; it < 16; ++it) {
    int idx = it * 256 + threadIdx.x;
    int oc = idx >> 6, orr = idx & 63;
    out[(size_t)(bc * 64 + oc) * R + br * 64 + orr] = t[orr * 66 + oc];
  }
}

// ---- prepA: cast x (f32) into A-frag-chunk tiles. Tile (by,kt) = x[by*128..][kt*64..], 8192 f16.
// Chunk c = ks*8+rb, lane l, elem j: A[rb*16+(l&15)][ks*32+(l>>4)*8+j]. Consumer ds_reads are the
// proven conflict-free (chunk*64+lane)*8 pattern; staging is global_load_lds-compatible (linear).
__global__ __launch_bounds__(256) void k_prepA(const float* __restrict__ x, f16* __restrict__ xhT) {
  int kt = blockIdx.x, by = blockIdx.y;
  f16* dst = xhT + ((size_t)(by * 16 + kt) << 13);
  int tid = threadIdx.x;
#pragma unroll
  for (int i = 0; i < 4; ++i) {
    int idx = i * 256 + tid;
    int chunk = idx >> 6, lane = idx & 63;
    int rb = chunk & 7, ks = chunk >> 3;
    int row = by * 128 + rb * 16 + (lane & 15);
    int kk = kt * 64 + ks * 32 + ((lane >> 4) << 3);
    const float* p = x + (size_t)row * DIM + kk;
    float4 lo = *(const float4*)p, hi = *(const float4*)(p + 4);
    f16x8 h;
    h[0] = (f16)lo.x; h[1] = (f16)lo.y; h[2] = (f16)lo.z; h[3] = (f16)lo.w;
    h[4] = (f16)hi.x; h[5] = (f16)hi.y; h[6] = (f16)hi.z; h[7] = (f16)hi.w;
    *(f16x8*)(dst + (size_t)idx * 8) = h;
  }
}

// ---- prepB: Wq[k][n] (f32 [1024][6144]) -> B-frag-chunk tiles. Tile (bx,kt): B[n][k] with
// n = bx*128 + rb*16 + (l&15), k = kt*64 + ks*32 + (l>>4)*8 + j. Per j the 16 (l&15)-lanes read
// 64B contiguous from Wq -> acceptably coalesced for a 25 MB one-shot prep.
__global__ __launch_bounds__(256) void k_prepB(const float* __restrict__ Wq, f16* __restrict__ WqTf) {
  int kt = blockIdx.x, bx = blockIdx.y;
  f16* dst = WqTf + ((size_t)(bx * 16 + kt) << 13);
  int tid = threadIdx.x;
#pragma unroll
  for (int i = 0; i < 4; ++i) {
    int idx = i * 256 + tid;
    int chunk = idx >> 6, lane = idx & 63;
    int rb = chunk & 7, ks = chunk >> 3;
    int n = bx * 128 + rb * 16 + (lane & 15);
    int kk = kt * 64 + ks * 32 + ((lane >> 4) << 3);
    f16x8 h;
#pragma unroll
    for (int j = 0; j < 8; ++j) h[j] = (f16)Wq[(size_t)(kk + j) * NCOLS + n];
    *(f16x8*)(dst + (size_t)idx * 8) = h;
  }
}

// ---------------- qkv GEMM v2 (R14): m97 pattern — global_load_lds staging of frag tiles ----------------
// Both operands pre-arranged in frag-chunk order: stage 16KB tiles async, ds_read conflict-free
// frags, MFMA. Removes the f32 loads + cvt VALU that dominated the old staging loop.
__global__ __launch_bounds__(256) void k_gemm_qkv(const f16* __restrict__ xhT, const f16* __restrict__ WqTf,
                                                  f16* __restrict__ q6) {
  __shared__ f16 sa[8192];
  __shared__ f16 sb[8192];
  int bx = blockIdx.x, by = blockIdx.y;
  int tid = threadIdx.x, w = tid >> 6, l = tid & 63, q = l >> 4, c = l & 15;
  f32x4 acc[2][8];
  const f32x4 zf = {0.f, 0.f, 0.f, 0.f};
  for (int i = 0; i < 2; ++i) for (int j = 0; j < 8; ++j) acc[i][j] = zf;

  for (int kt = 0; kt < 16; ++kt) {
    const f16* ta = xhT + ((size_t)(by * 16 + kt) << 13);
    const f16* tb = WqTf + ((size_t)(bx * 16 + kt) << 13);
    __syncthreads();
#pragma unroll
    for (int i = 0; i < 4; ++i) {
      int e = (i * 256 + tid) * 8;
      __builtin_amdgcn_global_load_lds((const __attribute__((address_space(1))) void*)(ta + e),
                                       (__attribute__((address_space(3))) void*)(sa + e), 16, 0, 0);
      __builtin_amdgcn_global_load_lds((const __attribute__((address_space(1))) void*)(tb + e),
                                       (__attribute__((address_space(3))) void*)(sb + e), 16, 0, 0);
    }
    __syncthreads();
#pragma unroll
    for (int ks = 0; ks < 2; ++ks) {
      f16x8 af[2], bf[8];
#pragma unroll
      for (int tr = 0; tr < 2; ++tr)
        af[tr] = *(const f16x8*)(sa + ((ks * 8 + w * 2 + tr) * 64 + l) * 8);
#pragma unroll
      for (int tc = 0; tc < 8; ++tc)
        bf[tc] = *(const f16x8*)(sb + ((ks * 8 + tc) * 64 + l) * 8);
#pragma unroll
      for (int tr = 0; tr < 2; ++tr)
#pragma unroll
        for (int tc = 0; tc < 8; ++tc)
          acc[tr][tc] = __builtin_amdgcn_mfma_f32_16x16x32_f16(af[tr], bf[tc], acc[tr][tc], 0, 0, 0);
    }
  }
  // epilogue: scatter into qu(0) ku(1) vu(2) qc(3) kc(4) vcT(5); scale qu,qc by dh^-0.5
#pragma unroll
  for (int tr = 0; tr < 2; ++tr)
#pragma unroll
    for (int tc = 0; tc < 8; ++tc)
#pragma unroll
      for (int r = 0; r < 4; ++r) {
        int row = by * 128 + w * 32 + tr * 16 + q * 4 + r;
        int col = bx * 128 + tc * 16 + c;
        float v = acc[tr][tc][r];
        int t = col >> 10, head = (col >> 6) & 15, dh = col & 63;
        if (t == 0 || t == 3) v *= 0.125f;
        if (t == 5) q6[(size_t)5 * NHSD + (size_t)(head * DH + dh) * SEQ + row] = (f16)v;
        else        q6[(size_t)t * NHSD + (size_t)(head * SEQ + row) * DH + dh] = (f16)v;
      }
}

// ---------------- t1 + lk tile producer (each distinct tile computed ONCE, stored frag-ordered) ----------------
__global__ __launch_bounds__(256) void k_t1lk(const f16* __restrict__ q6, f16* __restrict__ t1T,
                                              f16* __restrict__ lkT) {
  __shared__ f16 st[128 * 128];
  int head = blockIdx.x / 272;
  int p = blockIdx.x % 272;
  bool is_lk = (p >= 136);
  int RB, CB;        // row-block (i or k), col-block (j)
  f16* dst;
  if (is_lk) {
    int p2 = p - 136;
    int K = 0, off = 0;
    while (off + (16 - K) <= p2) { off += 16 - K; ++K; }
    RB = K; CB = K + (p2 - off);
    dst = lkT + ((size_t)(head * NTILE + p2) << 14);
  } else {
    int I = 0;
    while ((I + 1) * (I + 2) / 2 <= p) ++I;
    RB = I; CB = p - I * (I + 1) / 2;
    dst = t1T + ((size_t)(head * NTILE + p) << 14);
  }
  const f16* Ah = q6 + (size_t)(is_lk ? 0 : 3) * NHSD + (size_t)head * SEQ * DH;  // qu_s / qc_s
  const f16* Bh = q6 + (size_t)(is_lk ? 1 : 2) * NHSD + (size_t)head * SEQ * DH;  // ku / vu
  int tid = threadIdx.x, w = tid >> 6, l = tid & 63, q = l >> 4, c = l & 15;
  const f32x4 zf = {0.f, 0.f, 0.f, 0.f};
  f32x4 tacc[2][8];
  for (int tr = 0; tr < 2; ++tr) for (int tc = 0; tc < 8; ++tc) tacc[tr][tc] = zf;
#pragma unroll
  for (int ks = 0; ks < 2; ++ks) {
    f16x8 aq[2], bf[8];
#pragma unroll
    for (int tr = 0; tr < 2; ++tr)
      aq[tr] = *(const f16x8*)(Ah + (size_t)(RB * 128 + w * 32 + tr * 16 + c) * DH + ks * 32 + q * 8);
#pragma unroll
    for (int tc = 0; tc < 8; ++tc)
      bf[tc] = *(const f16x8*)(Bh + (size_t)(CB * 128 + tc * 16 + c) * DH + ks * 32 + q * 8);
#pragma unroll
    for (int tr = 0; tr < 2; ++tr)
#pragma unroll
      for (int tc = 0; tc < 8; ++tc)
        tacc[tr][tc] = __builtin_amdgcn_mfma_f32_16x16x32_f16(aq[tr], bf[tc], tacc[tr][tc], 0, 0, 0);
  }
  // epilogue: mask (+sigmoid for lk) -> LDS row-major swizzled, own rows
#pragma unroll
  for (int tr = 0; tr < 2; ++tr)
#pragma unroll
    for (int tc = 0; tc < 8; ++tc)
#pragma unroll
      for (int r = 0; r < 4; ++r) {
        int row = w * 32 + tr * 16 + q * 4 + r;
        int col = tc * 16 + c;
        int rg = RB * 128 + row, cg = CB * 128 + col;
        float v = tacc[tr][tc][r];
        f16 ov;
        if (is_lk) ov = (cg > rg) ? (f16)__builtin_amdgcn_rcpf(1.f + __expf(-v)) : (f16)(0.f);
        else       ov = (cg <= rg) ? (f16)v : (f16)(0.f);
        st[(row << 7) + (((col >> 3) ^ (row & 15)) << 3) + (col & 7)] = ov;
      }
  __syncthreads();
  // re-read in frag order, write 16B-coalesced
#pragma unroll
  for (int i = 0; i < 8; ++i) {
    int ch = i * 256 + tid;
    int ks = ch >> 9, rb = (ch >> 6) & 7, ln = ch & 63;
    int qq = ln >> 4, cc = ln & 15;
    int row = rb * 16 + cc, cchunk = ks * 4 + qq;
    f16x8 v = *(const f16x8*)(st + (row << 7) + ((cchunk ^ (row & 15)) << 3));
    *(f16x8*)(dst + (size_t)ch * 8) = v;
  }
}

// ---------------- I-pair split-K flash (R14: J-DESCENDING for cross-split L2 alignment) ----------------
// R13 post-mortem: vmcnt is FIFO — t1 af global loads (younger) force prefetch (older) completion,
// so dbuf never overlapped. R14 keeps the structure but reverses the J-loop: all splits of a pair
// start at J=I1, temporally aligning their shared t1(I,J) read streams -> L2 hits instead of HBM
// re-fetch (t1 is ~2/3 of the 682 MB logical traffic; FETCH was 245 MB).
__global__ __launch_bounds__(512, 1) void k_flash(const f16* __restrict__ q6, const f16* __restrict__ t1T,
                                                  const f16* __restrict__ lkT,
                                                  f16* __restrict__ pO, float* __restrict__ pML) {
  __shared__ f16 lkb[2][128 * 128];  // double-buffered staged lk tile (B-frag chunk order)
  __shared__ f16 Pb[256 * 128];      // P for both I-tiles (row-swizzled); own-wave rows only
  int bid = blockIdx.x;
  int head = ((bid & 7) << 1) | ((bid >> 3) & 1);
  int r2 = 31 - (bid >> 4);          // reversed: big pairs (a=7) dispatch first
  int a = 0, s = 0;
  {
    int acc = 0;
    for (int aa = 0; aa < 8; ++aa) {
      int si = ns2(aa);
      if (r2 >= acc && r2 < acc + si) { a = aa; s = r2 - acc; }
      acc += si;
    }
  }
  int I1 = 2 * a + 1;
  int S_ = ns2(a);
  int C = (I1 + 1) * (I1 + 2) / 2;
  int K0 = 16, K1 = 0;               // midpoint equal-cost partition of K in [0, I1]
  {
    int p = 0;
    for (int K = 0; K <= I1; ++K) {
      int cost = I1 - K + 1;
      int seg = ((2 * p + cost) * S_) / (2 * C);
      if (seg == s) { if (K < K0) K0 = K; K1 = K + 1; }
      p += cost;
    }
  }

  const f16* qc = q6 + (size_t)3 * NHSD + (size_t)head * SEQ * DH;   // pre-scaled by dh^-0.5
  const f16* kc = q6 + (size_t)4 * NHSD + (size_t)head * SEQ * DH;
  const f16* vt = q6 + (size_t)5 * NHSD + (size_t)head * DH * SEQ;   // vc transposed [64][2048]
  int tid = threadIdx.x, w = tid >> 6, l = tid & 63, q = l >> 4, c = l & 15;
  int wi = w & 3, big = w >> 2;
  int IB = 2 * a + big;              // this wave's I-tile
  const f16* t1h = t1T + ((size_t)(head * NTILE + IB * (IB + 1) / 2) << 14);
  const f16* lkh = lkT + ((size_t)(head * NTILE) << 14);

  // qc_s(IB) A-frags for the Sc MFMA (this wave's 32 rows)
  f16x8 a_qc[2][2];
#pragma unroll
  for (int tr = 0; tr < 2; ++tr)
#pragma unroll
    for (int ks = 0; ks < 2; ++ks)
      a_qc[tr][ks] = *(const f16x8*)(qc + (size_t)(IB * 128 + wi * 32 + tr * 16 + c) * DH + ks * 32 + q * 8);

  f32x4 su[2][8], oacc[2][4];
  float m_i[2][4], l_i[2][4];
  const f32x4 zf = {0.f, 0.f, 0.f, 0.f};
  for (int tr = 0; tr < 2; ++tr) for (int tv = 0; tv < 4; ++tv) oacc[tr][tv] = zf;
  for (int tr = 0; tr < 2; ++tr) for (int r = 0; r < 4; ++r) { m_i[tr][r] = -INFINITY; l_i[tr][r] = 0.f; }

  for (int K = K0; K < K1; ++K) {
    int offK = 16 * K - (K * (K - 1)) / 2;
#pragma unroll
    for (int tr = 0; tr < 2; ++tr) for (int tc = 0; tc < 8; ++tc) su[tr][tc] = zf;

    // prologue: stage lk(K, I1) into buf 0 (WAR vs previous reads handled by barrier)
    __syncthreads();
    {
      const f16* lt = lkh + ((size_t)(offK + (I1 - K)) << 14);
#pragma unroll
      for (int i = 0; i < 4; ++i) {
        int e = (i * 512 + tid) * 8;
        __builtin_amdgcn_global_load_lds((const __attribute__((address_space(1))) void*)(lt + e),
                                         (__attribute__((address_space(3))) void*)(&lkb[0][0] + e), 16, 0, 0);
      }
    }
    int pb = 0;
    for (int J = I1; J >= K; --J) {
      __syncthreads();   // buf[pb] staged
      if (J > K) {       // prefetch previous-J tile into the idle buffer
        const f16* ln = lkh + ((size_t)(offK + (J - 1 - K)) << 14);
#pragma unroll
        for (int i = 0; i < 4; ++i) {
          int e = (i * 512 + tid) * 8;
          __builtin_amdgcn_global_load_lds((const __attribute__((address_space(1))) void*)(ln + e),
                                           (__attribute__((address_space(3))) void*)(&lkb[pb ^ 1][0] + e), 16, 0, 0);
        }
      }
      if (J <= IB) {     // wave-uniform: I0 waves skip J = I1
        const f16* tt = t1h + ((size_t)J << 14);
#pragma unroll
        for (int ks = 0; ks < 4; ++ks) {
          f16x8 af[2], bf[8];
#pragma unroll
          for (int tr = 0; tr < 2; ++tr)
            af[tr] = *(const f16x8*)(tt + (size_t)((ks * 8 + wi * 2 + tr) * 64 + l) * 8);
#pragma unroll
          for (int tc = 0; tc < 8; ++tc)
            bf[tc] = *(const f16x8*)(&lkb[pb][0] + ((ks * 8 + tc) * 64 + l) * 8);
#pragma unroll
          for (int tr = 0; tr < 2; ++tr)
#pragma unroll
            for (int tc = 0; tc < 8; ++tc)
              su[tr][tc] = __builtin_amdgcn_mfma_f32_16x16x32_f16(af[tr], bf[tc], su[tr][tc], 0, 0, 0);
        }
      }
      pb ^= 1;
    }

    if (K <= IB) {       // wave-uniform epilogue; K=I1 contributes nothing to I0 waves
      // scores = Sc - silu(Su)
#pragma unroll
      for (int tr = 0; tr < 2; ++tr)
#pragma unroll
        for (int tc = 0; tc < 8; ++tc)
#pragma unroll
          for (int r = 0; r < 4; ++r) {
            float v = su[tr][tc][r];
            su[tr][tc][r] = -v * __builtin_amdgcn_rcpf(1.f + __expf(-v));
          }
#pragma unroll
      for (int ks = 0; ks < 2; ++ks) {
        f16x8 bk[8];
#pragma unroll
        for (int tc = 0; tc < 8; ++tc)
          bk[tc] = *(const f16x8*)(kc + (size_t)(K * 128 + tc * 16 + c) * DH + ks * 32 + q * 8);
#pragma unroll
        for (int tr = 0; tr < 2; ++tr)
#pragma unroll
          for (int tc = 0; tc < 8; ++tc)
            su[tr][tc] = __builtin_amdgcn_mfma_f32_16x16x32_f16(a_qc[tr][ks], bk[tc], su[tr][tc], 0, 0, 0);
      }
      if (K == IB) {     // strict causal mask inside the diagonal block
#pragma unroll
        for (int tr = 0; tr < 2; ++tr)
#pragma unroll
          for (int tc = 0; tc < 8; ++tc)
#pragma unroll
            for (int r = 0; r < 4; ++r) {
              int rg = wi * 32 + tr * 16 + q * 4 + r;
              int cg = tc * 16 + c;
              if (cg > rg) su[tr][tc][r] = -INFINITY;
            }
      }
      // online softmax (per-row, shuffle across low-4 lane bits)
#pragma unroll
      for (int tr = 0; tr < 2; ++tr)
#pragma unroll
        for (int r = 0; r < 4; ++r) {
          float mx = su[tr][0][r];
#pragma unroll
          for (int tc = 1; tc < 8; ++tc) mx = fmaxf(mx, su[tr][tc][r]);
          mx = fmaxf(mx, __shfl_xor(mx, 1)); mx = fmaxf(mx, __shfl_xor(mx, 2));
          mx = fmaxf(mx, __shfl_xor(mx, 4)); mx = fmaxf(mx, __shfl_xor(mx, 8));
          float mnew  = fmaxf(m_i[tr][r], mx);
          float alpha = __expf(m_i[tr][r] - mnew);
          float ssum = 0.f;
#pragma unroll
          for (int tc = 0; tc < 8; ++tc) {
            float pp = __expf(su[tr][tc][r] - mnew);
            su[tr][tc][r] = pp;
            ssum += pp;
          }
          ssum += __shfl_xor(ssum, 1); ssum += __shfl_xor(ssum, 2);
          ssum += __shfl_xor(ssum, 4); ssum += __shfl_xor(ssum, 8);
          l_i[tr][r] = l_i[tr][r] * alpha + ssum;
          m_i[tr][r] = mnew;
#pragma unroll
          for (int tv = 0; tv < 4; ++tv) oacc[tr][tv][r] *= alpha;
        }
      // P -> Pb (own 32-row region of the 256-row buffer; no barrier)
#pragma unroll
      for (int tr = 0; tr < 2; ++tr)
#pragma unroll
        for (int tc = 0; tc < 8; ++tc)
#pragma unroll
          for (int r = 0; r < 4; ++r) {
            int row = w * 32 + tr * 16 + q * 4 + r;    // 0..255
            int col = tc * 16 + c;
            Pb[(row << 7) + (((col >> 3) ^ (row & 15)) << 3) + (col & 7)] = (f16)su[tr][tc][r];
          }
      // PV: A = P (own Pb rows), B = vcT from global
#pragma unroll
      for (int ks = 0; ks < 4; ++ks) {
        int ck = ks * 4 + q;
        f16x8 af[2], bv[4];
#pragma unroll
        for (int tr = 0; tr < 2; ++tr)
          af[tr] = *(const f16x8*)(Pb + ((w * 32 + tr * 16 + c) << 7) + ((ck ^ c) << 3));
#pragma unroll
        for (int tv = 0; tv < 4; ++tv)
          bv[tv] = *(const f16x8*)(vt + (size_t)(tv * 16 + c) * SEQ + K * 128 + ks * 32 + q * 8);
#pragma unroll
        for (int tr = 0; tr < 2; ++tr)
#pragma unroll
          for (int tv = 0; tv < 4; ++tv)
            oacc[tr][tv] = __builtin_amdgcn_mfma_f32_16x16x32_f16(af[tr], bv[tv], oacc[tr][tv], 0, 0, 0);
      }
    }
  }

  // ---- unnormalized partial: slot = head*64 + prefix(IB) + s ----
  int slot = head * SLOTS_PER_HEAD + slot_base(IB) + s;
  f16* po = pO + (size_t)slot * (128 * 64);
  float* pml = pML + (size_t)slot * 256;
  if (c == 0) {
#pragma unroll
    for (int tr = 0; tr < 2; ++tr)
#pragma unroll
      for (int r = 0; r < 4; ++r) {
        int row = wi * 32 + tr * 16 + q * 4 + r;
        pml[row] = m_i[tr][r];
        pml[128 + row] = l_i[tr][r];
      }
  }
#pragma unroll
  for (int tr = 0; tr < 2; ++tr)
#pragma unroll
    for (int tv = 0; tv < 4; ++tv)
#pragma unroll
      for (int r = 0; r < 4; ++r) {
        int row = wi * 32 + tr * 16 + q * 4 + r;
        int col = tv * 16 + c;
        po[row * 64 + col] = (f16)oacc[tr][tv][r];
      }
}

// ---------------- merge partials -> oh [2048][1024] f16 ----------------
__global__ __launch_bounds__(256) void k_merge(const f16* __restrict__ pO, const float* __restrict__ pML,
                                               f16* __restrict__ oh) {
  int head = blockIdx.x >> 4, I = blockIdx.x & 15;
  int S_ = ns2(I >> 1);
  int tid = threadIdx.x;
  int row = tid >> 1, half = tid & 1;
  int base = head * SLOTS_PER_HEAD + slot_base(I);
  float m[MAXS], lv[MAXS];
  float mstar = -INFINITY;
#pragma unroll
  for (int s = 0; s < MAXS; ++s)
    if (s < S_) {
      m[s] = pML[(size_t)(base + s) * 256 + row];
      lv[s] = pML[(size_t)(base + s) * 256 + 128 + row];
      mstar = fmaxf(mstar, m[s]);
    }
  float wt[MAXS];
  float lsum = 0.f;
#pragma unroll
  for (int s = 0; s < MAXS; ++s)
    if (s < S_) {
      wt[s] = __expf(m[s] - mstar);   // empty partials (m=-inf) get weight 0
      lsum += lv[s] * wt[s];
    }
  float rinv = __builtin_amdgcn_rcpf(lsum);
#pragma unroll
  for (int cc = 0; cc < 32; cc += 8) {
    float acc[8] = {0.f, 0.f, 0.f, 0.f, 0.f, 0.f, 0.f, 0.f};
#pragma unroll
    for (int s = 0; s < MAXS; ++s)
      if (s < S_) {
        f16x8 v = *(const f16x8*)(pO + (size_t)(base + s) * 8192 + row * 64 + half * 32 + cc);
#pragma unroll
        for (int e = 0; e < 8; ++e) acc[e] += wt[s] * (float)v[e];
      }
    f16x8 o;
#pragma unroll
    for (int e = 0; e < 8; ++e) o[e] = (f16)(acc[e] * rinv);
    *(f16x8*)(oh + (size_t)(I * 128 + row) * DIM + head * 64 + half * 32 + cc) = o;
  }
}

// ---------------- final GEMM: oh[2048,1024] @ WoT[1024,1024]^T -> fp32 out ----------------
__global__ __launch_bounds__(256) void k_gemm_out(const f16* __restrict__ A, const f16* __restrict__ B,
                                                  float* __restrict__ out) {
  __shared__ f16 sa[128 * 72];
  __shared__ f16 sb[128 * 72];
  int bx = blockIdx.x, by = blockIdx.y;
  int tid = threadIdx.x, w = tid >> 6, l = tid & 63, q = l >> 4, c = l & 15;
  f32x4 acc[2][8];
  const f32x4 zf = {0.f, 0.f, 0.f, 0.f};
  for (int i = 0; i < 2; ++i) for (int j = 0; j < 8; ++j) acc[i][j] = zf;
  for (int kt = 0; kt < DIM / 64; ++kt) {
    __syncthreads();
#pragma unroll
    for (int it = 0; it < 4; ++it) {
      int idx = it * 256 + tid; int r = idx >> 3, ch = idx & 7;
      *(float4*)(sa + r * 72 + ch * 8) = *(const float4*)(A + (size_t)(by * 128 + r) * DIM + kt * 64 + ch * 8);
      *(float4*)(sb + r * 72 + ch * 8) = *(const float4*)(B + (size_t)(bx * 128 + r) * DIM + kt * 64 + ch * 8);
    }
    __syncthreads();
#pragma unroll
    for (int ks = 0; ks < 2; ++ks) {
      f16x8 af[2], bf[8];
#pragma unroll
      for (int tr = 0; tr < 2; ++tr) af[tr] = *(const f16x8*)(sa + (w * 32 + tr * 16 + c) * 72 + ks * 32 + q * 8);
#pragma unroll
      for (int tc = 0; tc < 8; ++tc) bf[tc] = *(const f16x8*)(sb + (tc * 16 + c) * 72 + ks * 32 + q * 8);
#pragma unroll
      for (int tr = 0; tr < 2; ++tr)
#pragma unroll
        for (int tc = 0; tc < 8; ++tc)
          acc[tr][tc] = __builtin_amdgcn_mfma_f32_16x16x32_f16(af[tr], bf[tc], acc[tr][tc], 0, 0, 0);
    }
  }
#pragma unroll
  for (int tr = 0; tr < 2; ++tr)
#pragma unroll
    for (int tc = 0; tc < 8; ++tc)
#pragma unroll
      for (int r = 0; r < 4; ++r) {
        int row = by * 128 + w * 32 + tr * 16 + q * 4 + r;
        int col = bx * 128 + tc * 16 + c;
        out[(size_t)row * DIM + col] = acc[tr][tc][r];
      }
}

extern "C" void kernel_launch(void* const* d_in, const int* in_sizes, int n_in,
                              void* d_out, int out_size, void* d_ws, size_t ws_size,
                              hipStream_t stream) {
  const float* x  = (const float*)d_in[0];
  const float* Wq = (const float*)d_in[1];
  const float* Wo = (const float*)d_in[2];
  float* out = (float*)d_out;

  f16* ws = (f16*)d_ws;
  size_t off = 0;
  f16* q6   = ws + off; off += (size_t)6 * NHSD;                        // 25.2 MB
  f16* xhT  = ws + off; off += (size_t)SEQ * DIM;                       // 4.2 MB (A-frag tiles)
  f16* WqTf = ws + off; off += (size_t)NCOLS * DIM;                     // 12.6 MB (B-frag tiles)
  f16* WoT  = ws + off; off += (size_t)DIM * DIM;                       // 2.1 MB
  f16* oh   = ws + off; off += (size_t)SEQ * DIM;                       // 4.2 MB
  f16* pO   = ws + off; off += (size_t)NH * SLOTS_PER_HEAD * 128 * 64;  // 16.8 MB
  f16* lkT  = ws + off; off += (size_t)NH * NTILE * 128 * 128;          // 71.3 MB
  f16* t1T  = ws + off; off += (size_t)NH * NTILE * 128 * 128;          // 71.3 MB
  float* pML = (float*)(ws + off); off += (size_t)NH * SLOTS_PER_HEAD * 256 * 2; // 1.05 MB
  // total ~209 MB of workspace

  k_prepA<<<dim3(16, 16), 256, 0, stream>>>(x, xhT);
  k_prepB<<<dim3(16, 48), 256, 0, stream>>>(Wq, WqTf);
  k_tcast<<<dim3(DIM / 64, DIM / 64), 256, 0, stream>>>(Wo, WoT, DIM, DIM);
  k_gemm_qkv<<<dim3(NCOLS / 128, SEQ / 128), 256, 0, stream>>>(xhT, WqTf, q6);
  k_t1lk<<<NH * 272, 256, 0, stream>>>(q6, t1T, lkT);
  k_flash<<<NH * 32, 512, 0, stream>>>(q6, t1T, lkT, pO, pML);
  k_merge<<<NH * 16, 256, 0, stream>>>(pO, pML, oh);
  k_gemm_out<<<dim3(DIM / 128, SEQ / 128), 256, 0, stream>>>(oh, WoT, out);
}